// Round 2
// baseline (852.348 us; speedup 1.0000x reference)
//
#include <hip/hip_runtime.h>
#include <hip/hip_bf16.h>
#include <stdint.h>

// Problem constants (match reference)
constexpr int NUM_NODES = 120000;
constexpr int Dd = 128;   // graph_emb_size
constexpr int Tn = 10;    // time steps
constexpr int TP = 12;    // padded T for aligned float4 LDS reads
constexpr int Bb = 64;    // batch
constexpr int Rr = 4;     // relations
constexpr int Nn = 64;    // neighbors
constexpr int Cc = 64;    // channels
constexpr int Ii = 64;    // influence size
constexpr int Ll = 8;     // levels
constexpr int G  = 4;     // sequences per block

// ---------------------------------------------------------------------------
// Weight transpose: [.., c, cin, k] -> [.., cin, k, c] so lanes (c) coalesce.
// ---------------------------------------------------------------------------
extern "C" __global__ void prep_kernel(const float* __restrict__ w1_0,
                                       const float* __restrict__ w2_0,
                                       const float* __restrict__ down_w,
                                       const float* __restrict__ w1s,
                                       const float* __restrict__ w2s,
                                       float* __restrict__ wA, float* __restrict__ wB,
                                       float* __restrict__ wD, float* __restrict__ wL1,
                                       float* __restrict__ wL2) {
  int i0 = blockIdx.x * blockDim.x + threadIdx.x;
  int stride = gridDim.x * blockDim.x;
  // w1_0 [r][c][cin=128][k=2] -> wA [r][cin][k][c]
  for (int e = i0; e < Rr * Cc * Dd * 2; e += stride) {
    int k = e & 1, cin = (e >> 1) & 127, c = (e >> 8) & 63, r = e >> 14;
    wA[((r * Dd + cin) * 2 + k) * Cc + c] = w1_0[e];
  }
  // w2_0 [r][c][cin=64][k=2] -> wB [r][cin][k][c]
  for (int e = i0; e < Rr * Cc * Cc * 2; e += stride) {
    int k = e & 1, cin = (e >> 1) & 63, c = (e >> 7) & 63, r = e >> 13;
    wB[((r * Cc + cin) * 2 + k) * Cc + c] = w2_0[e];
  }
  // down_w [r][c][cin=128][1] -> wD [r][cin][c]
  for (int e = i0; e < Rr * Cc * Dd; e += stride) {
    int cin = e & 127, c = (e >> 7) & 63, r = e >> 13;
    wD[(r * Dd + cin) * Cc + c] = down_w[e];
  }
  // w1/w2 [r][l=7][c][cin=64][k=2] -> [r][l][cin][k][c]
  for (int e = i0; e < Rr * 7 * Cc * Cc * 2; e += stride) {
    int k = e & 1, cin = (e >> 1) & 63, c = (e >> 7) & 63;
    int l = (e >> 13) % 7, r = e / (7 * Cc * Cc * 2);
    int o = (((r * 7 + l) * Cc + cin) * 2 + k) * Cc + c;
    wL1[o] = w1s[e];
    wL2[o] = w2s[e];
  }
}

// ---------------------------------------------------------------------------
// Causal dilated conv over one sequence held in LDS [CIN][TP].
// All lanes read the SAME LDS address (broadcast, conflict-free);
// weights are lane-coalesced from the transposed layout.
// ---------------------------------------------------------------------------
template <int CIN, int DIL, bool K2>
__device__ __forceinline__ void convT(const float* __restrict__ in,  // [CIN][TP]
                                      const float* __restrict__ wt,  // [(cin*2+k)*64+c] or [cin*64+c]
                                      int c, float bias, float acc[Tn]) {
#pragma unroll
  for (int t = 0; t < Tn; ++t) acc[t] = bias;
#pragma unroll 2
  for (int cin = 0; cin < CIN; ++cin) {
    const float* row = in + cin * TP;
    float4 p0 = *(const float4*)(row);
    float4 p1 = *(const float4*)(row + 4);
    float2 p2 = *(const float2*)(row + 8);
    float x[Tn] = {p0.x, p0.y, p0.z, p0.w, p1.x, p1.y, p1.z, p1.w, p2.x, p2.y};
    float w0v = 0.f, w1v;
    if (K2) {
      if (DIL < Tn) w0v = wt[(cin * 2 + 0) * Cc + c];
      w1v = wt[(cin * 2 + 1) * Cc + c];
    } else {
      w1v = wt[cin * Cc + c];
    }
#pragma unroll
    for (int t = 0; t < Tn; ++t) {
      acc[t] = fmaf(w1v, x[t], acc[t]);
      if (K2 && t >= DIL) acc[t] = fmaf(w0v, x[t - DIL], acc[t]);
    }
  }
}

// ---------------------------------------------------------------------------
// Main: gather + 8-level TCN + masked per-block partial reduction.
// Block: 256 threads = 4 sequences x 64 channels. Grid: R * 4096/G = 4096.
// ---------------------------------------------------------------------------
extern "C" __global__ void __launch_bounds__(256)
tcn_kernel(const float* __restrict__ emb, const int* __restrict__ align_,
           const int* __restrict__ nidx, const int* __restrict__ nmask,
           const float* __restrict__ b1_0, const float* __restrict__ b2_0,
           const float* __restrict__ down_b, const float* __restrict__ b1s,
           const float* __restrict__ b2s,
           const float* __restrict__ wA, const float* __restrict__ wB,
           const float* __restrict__ wD, const float* __restrict__ wL1,
           const float* __restrict__ wL2, float* __restrict__ P) {
  __shared__ float xs[G][Dd][TP];  // 24 KB  level-0 input
  __shared__ float hs[G][Cc][TP];  // 12 KB  residual state
  __shared__ float ys[G][Cc][TP];  // 12 KB  inter-conv buffer
  __shared__ int rowid[G][Tn];
  __shared__ float mkv[G];

  const int tid = threadIdx.x;
  const int c = tid & 63, g = tid >> 6;
  const int blk = blockIdx.x;
  const int r = blk >> 10;              // 1024 blocks per relation
  const int mb = (blk & 1023) * G;      // first sequence in relation
  const int b = mb >> 6;                // batch index (shared by all g)

  // per-(g,t) gather row ids (+ mask)
  if (tid < G * Tn) {
    int gg = tid / Tn, t = tid - gg * Tn;
    int m = mb + gg;
    int bb = m >> 6, n = m & 63;
    int ent = nidx[(bb * Rr + r) * Nn + n];
    int msk = nmask[(bb * Rr + r) * Nn + n];
    int s = align_[ent * Tn + t];
    rowid[gg][t] = (msk != 0 && s >= 0) ? s : -1;
    if (t == 0) mkv[gg] = (msk != 0) ? 1.0f : 0.0f;
  }
  __syncthreads();

  // gather embeddings -> xs[g][d][t]
  for (int i = tid; i < G * Tn * Dd; i += 256) {
    int d = i & 127;
    int gt = i >> 7;
    int gg = gt / Tn, t = gt - gg * Tn;
    int row = rowid[gg][t];
    float v = (row >= 0) ? emb[(size_t)(t * NUM_NODES + row) * Dd + d] : 0.0f;
    xs[gg][d][t] = v;
  }
  __syncthreads();

  float acc1[Tn], acc2[Tn], hreg[Tn];

  // ---- level 0 ----
  convT<Dd, 1, true>(&xs[g][0][0], wA + r * (Dd * 2 * Cc), c, b1_0[r * Cc + c], acc1);
#pragma unroll
  for (int t = 0; t < Tn; ++t) ys[g][c][t] = fmaxf(acc1[t], 0.f);
  __syncthreads();
  convT<Cc, 1, true>(&ys[g][0][0], wB + r * (Cc * 2 * Cc), c, b2_0[r * Cc + c], acc2);
  convT<Dd, 1, false>(&xs[g][0][0], wD + r * (Dd * Cc), c, down_b[r * Cc + c], acc1);
#pragma unroll
  for (int t = 0; t < Tn; ++t) {
    hreg[t] = fmaxf(fmaxf(acc2[t], 0.f) + acc1[t], 0.f);
    hs[g][c][t] = hreg[t];
  }
  __syncthreads();

  // ---- levels 1..7 ----
#define LVL(lvl, DILv)                                                          \
  {                                                                             \
    const float* w1p = wL1 + (r * 7 + (lvl - 1)) * (Cc * 2 * Cc);               \
    const float* w2p = wL2 + (r * 7 + (lvl - 1)) * (Cc * 2 * Cc);               \
    float bb1 = b1s[(r * 7 + (lvl - 1)) * Cc + c];                              \
    float bb2 = b2s[(r * 7 + (lvl - 1)) * Cc + c];                              \
    convT<Cc, DILv, true>(&hs[g][0][0], w1p, c, bb1, acc1);                     \
    _Pragma("unroll") for (int t = 0; t < Tn; ++t) ys[g][c][t] =                \
        fmaxf(acc1[t], 0.f);                                                    \
    __syncthreads();                                                            \
    convT<Cc, DILv, true>(&ys[g][0][0], w2p, c, bb2, acc2);                     \
    _Pragma("unroll") for (int t = 0; t < Tn; ++t) {                            \
      hreg[t] = fmaxf(fmaxf(acc2[t], 0.f) + hreg[t], 0.f);                      \
      hs[g][c][t] = hreg[t];                                                    \
    }                                                                           \
    __syncthreads();                                                            \
  }
  LVL(1, 2)
  LVL(2, 4)
  LVL(3, 8)
  LVL(4, 16)
  LVL(5, 32)
  LVL(6, 64)
  LVL(7, 128)
#undef LVL

  // ---- epilogue: masked last-step, reduce 4 sequences -> per-block partial
  float lastv = hreg[Tn - 1] * mkv[g];
  __syncthreads();
  ys[g][c][0] = lastv;
  __syncthreads();
  if (tid < Cc) {
    float s = ys[0][tid][0] + ys[1][tid][0] + ys[2][tid][0] + ys[3][tid][0];
    int blkInB = (blk & 1023) & 15;  // 16 blocks per batch element
    P[(((r * Bb + b) * 16) + blkInB) * Cc + tid] = s;
  }
}

// ---------------------------------------------------------------------------
// out[b][i] = sum_r sum_c (sum_p P[r][b][p][c]) * rel_w[r][c][i]
// ---------------------------------------------------------------------------
extern "C" __global__ void reduce_kernel(const float* __restrict__ P,
                                         const float* __restrict__ rel_w,
                                         float* __restrict__ out) {
  __shared__ float Sl[Rr * Cc];
  int b = blockIdx.x, i = threadIdx.x;
  for (int idx = i; idx < Rr * Cc; idx += 64) {
    int rr = idx >> 6, cc = idx & 63;
    float s = 0.f;
    for (int p = 0; p < 16; ++p) s += P[((rr * Bb + b) * 16 + p) * Cc + cc];
    Sl[idx] = s;
  }
  __syncthreads();
  float acc = 0.f;
  for (int r = 0; r < Rr; ++r)
#pragma unroll
    for (int cc = 0; cc < Cc; ++cc)
      acc += Sl[r * Cc + cc] * rel_w[(r * Cc + cc) * Ii + i];
  out[b * Ii + i] = acc;
}

// ---------------------------------------------------------------------------
extern "C" void kernel_launch(void* const* d_in, const int* in_sizes, int n_in,
                              void* d_out, int out_size, void* d_ws, size_t ws_size,
                              hipStream_t stream) {
  const float* emb    = (const float*)d_in[0];
  const float* w1_0   = (const float*)d_in[1];
  const float* b1_0   = (const float*)d_in[2];
  const float* w2_0   = (const float*)d_in[3];
  const float* b2_0   = (const float*)d_in[4];
  const float* down_w = (const float*)d_in[5];
  const float* down_b = (const float*)d_in[6];
  const float* w1s    = (const float*)d_in[7];
  const float* b1s    = (const float*)d_in[8];
  const float* w2s    = (const float*)d_in[9];
  const float* b2s    = (const float*)d_in[10];
  const float* rel_w  = (const float*)d_in[11];
  const int* align_   = (const int*)d_in[12];
  const int* nidx     = (const int*)d_in[13];
  const int* nmask    = (const int*)d_in[14];

  float* ws  = (float*)d_ws;
  float* P   = ws;                 // 4*64*16*64      = 262144 floats
  float* wA  = P + 262144;         // 65536
  float* wB  = wA + 65536;         // 32768
  float* wD  = wB + 32768;         // 32768
  float* wL1 = wD + 32768;         // 229376
  float* wL2 = wL1 + 229376;       // 229376  -> total ~3.3 MB of ws

  prep_kernel<<<512, 256, 0, stream>>>(w1_0, w2_0, down_w, w1s, w2s, wA, wB, wD, wL1, wL2);
  tcn_kernel<<<Rr * (Bb * Nn / G), 256, 0, stream>>>(emb, align_, nidx, nmask, b1_0, b2_0,
                                                     down_b, b1s, b2s, wA, wB, wD, wL1, wL2, P);
  reduce_kernel<<<Bb, Cc, 0, stream>>>(P, rel_w, (float*)d_out);
}

// Round 3
// 73.009 us; speedup vs baseline: 11.6746x; 11.6746x over previous
//
#include <hip/hip_runtime.h>
#include <hip/hip_bf16.h>
#include <stdint.h>

constexpr int NUM_NODES = 120000;
constexpr int Tn = 10;
constexpr int Bb = 64, Rr = 4, Nn = 64, Cc = 64, Ii = 64;
constexpr int G  = 8;           // sequences per block
constexpr int M  = 80;          // columns per block (G*Tn)
constexpr int NT = 5;           // 16-wide col tiles
constexpr int RSTR  = 147456;   // per-relation Wf stride (bf16 elems)
constexpr int OFF0  = 0;        // L0 w1   [tap2][ct4][ks4][lane64][8]
constexpr int OFF1  = 16384;    // L0 down [ct4][ks4][lane64][8]
constexpr int OFF2  = 24576;    // L0 w2   [tap2][ct4][ks2][lane64][8]
constexpr int OFFL0 = 32768;    // levels  14 x [tap2][ct4][ks2][lane64][8]

typedef __attribute__((ext_vector_type(8))) short bf16x8;
typedef __attribute__((ext_vector_type(4))) float f32x4;
typedef __attribute__((ext_vector_type(4))) short s16x4;

__device__ __forceinline__ short f2bf(float f) {
  __hip_bfloat16 h = __float2bfloat16(f);
  return *reinterpret_cast<short*>(&h);
}

// ---------------------------------------------------------------------------
// Bake weights into per-lane MFMA A-fragments (bf16).
// A-frag for 16x16x32: lane holds A[ct*16 + (lane&15)][ks*32 + (lane>>4)*8 + j]
// ---------------------------------------------------------------------------
extern "C" __global__ void prep_kernel(const float* __restrict__ w1_0,
                                       const float* __restrict__ w2_0,
                                       const float* __restrict__ down_w,
                                       const float* __restrict__ w1s,
                                       const float* __restrict__ w2s,
                                       short* __restrict__ Wf) {
  int i0 = blockIdx.x * blockDim.x + threadIdx.x;
  int stride = gridDim.x * blockDim.x;
  for (int e = i0; e < Rr * RSTR; e += stride) {
    int r = e / RSTR, q = e - r * RSTR;
    float v;
    if (q < 16384) {                 // L0 w1 (CIN=128, 2 taps)
      int j = q & 7, lane = (q >> 3) & 63, ks = (q >> 9) & 3, ct = (q >> 11) & 3, tap = (q >> 13) & 1;
      int cout = ct * 16 + (lane & 15), cin = ks * 32 + (lane >> 4) * 8 + j;
      v = w1_0[((r * 64 + cout) * 128 + cin) * 2 + tap];
    } else if (q < 24576) {          // L0 down (CIN=128, 1 tap)
      int q2 = q - 16384;
      int j = q2 & 7, lane = (q2 >> 3) & 63, ks = (q2 >> 9) & 3, ct = (q2 >> 11) & 3;
      int cout = ct * 16 + (lane & 15), cin = ks * 32 + (lane >> 4) * 8 + j;
      v = down_w[(r * 64 + cout) * 128 + cin];
    } else if (q < 32768) {          // L0 w2 (CIN=64, 2 taps)
      int q2 = q - 24576;
      int j = q2 & 7, lane = (q2 >> 3) & 63, ks = (q2 >> 9) & 1, ct = (q2 >> 10) & 3, tap = (q2 >> 12) & 1;
      int cout = ct * 16 + (lane & 15), cin = ks * 32 + (lane >> 4) * 8 + j;
      v = w2_0[((r * 64 + cout) * 64 + cin) * 2 + tap];
    } else {                         // levels 1..7, convs w1/w2
      int q2 = q - 32768;
      int lc = q2 >> 13;             // 0..13
      int l = lc >> 1, jw = lc & 1;  // level (l+1), conv index
      int q3 = q2 & 8191;
      int j = q3 & 7, lane = (q3 >> 3) & 63, ks = (q3 >> 9) & 1, ct = (q3 >> 10) & 3, tap = (q3 >> 12) & 1;
      int cout = ct * 16 + (lane & 15), cin = ks * 32 + (lane >> 4) * 8 + j;
      const float* src = jw ? w2s : w1s;
      v = src[(((r * 7 + l) * 64 + cout) * 64 + cin) * 2 + tap];
    }
    Wf[e] = f2bf(v);
  }
}

// ---------------------------------------------------------------------------
// One causal-conv GEMM pass. X in LDS as [m][cin] bf16, XOR-swizzled.
// acc[tile] = bias; acc += W1*X[m] (+ W0*X[m-d] when NTAP==2, zero-row if t<d)
// ---------------------------------------------------------------------------
template <int KSN, int NTAP, int TAPOFF, int ROWB>
__device__ __forceinline__ void conv_pass(const char* __restrict__ src,
                                          const short* __restrict__ wf,
                                          const float* __restrict__ bias, int d,
                                          int lane, int ct, const int (&marr)[NT],
                                          const int (&tarr)[NT], f32x4 (&acc)[NT]) {
  const int chunk16 = (lane >> 4) * 16;
  float bv[4];
#pragma unroll
  for (int g = 0; g < 4; ++g) bv[g] = bias[ct * 16 + (lane >> 4) * 4 + g];
#pragma unroll
  for (int tile = 0; tile < NT; ++tile) acc[tile] = (f32x4){bv[0], bv[1], bv[2], bv[3]};
  bf16x8 af[NTAP][KSN];
#pragma unroll
  for (int tp = 0; tp < NTAP; ++tp)
#pragma unroll
    for (int ks = 0; ks < KSN; ++ks)
      af[tp][ks] = *(const bf16x8*)(wf + ((((tp + TAPOFF) * 4 + ct) * KSN + ks) * 64 + lane) * 8);
#pragma unroll
  for (int tile = 0; tile < NT; ++tile) {
    int m = marr[tile];
    int rb = m * ROWB, sw = (m & 7) << 4;
#pragma unroll
    for (int ks = 0; ks < KSN; ++ks) {
      bf16x8 bf = *(const bf16x8*)(src + rb + ((ks * 64 + chunk16) ^ sw));
      acc[tile] = __builtin_amdgcn_mfma_f32_16x16x32_bf16(af[NTAP - 1][ks], bf, acc[tile], 0, 0, 0);
    }
    if (NTAP == 2) {
      int m0 = (tarr[tile] >= d) ? (m - d) : M;  // row M = persistent zero row
      int rb0 = m0 * ROWB, sw0 = (m0 & 7) << 4;
#pragma unroll
      for (int ks = 0; ks < KSN; ++ks) {
        bf16x8 bf = *(const bf16x8*)(src + rb0 + ((ks * 64 + chunk16) ^ sw0));
        acc[tile] = __builtin_amdgcn_mfma_f32_16x16x32_bf16(af[0][ks], bf, acc[tile], 0, 0, 0);
      }
    }
  }
}

__device__ __forceinline__ void store_tiles(char* __restrict__ dst, int lane, int ct,
                                            const int (&marr)[NT], const f32x4 (&v)[NT]) {
  const int co = ct * 32 + (lane >> 4) * 8;
#pragma unroll
  for (int tile = 0; tile < NT; ++tile) {
    int m = marr[tile];
    s16x4 p;
#pragma unroll
    for (int g = 0; g < 4; ++g) p[g] = f2bf(v[tile][g]);
    *(s16x4*)(dst + m * 128 + (co ^ ((m & 7) << 4))) = p;
  }
}

// ---------------------------------------------------------------------------
// Main: gather->LDS bf16, 15 MFMA conv passes, masked lane-reduce epilogue.
// Block = 256 thr = 4 waves (wave = cout-tile), 8 sequences. Grid = 2048.
// ---------------------------------------------------------------------------
extern "C" __global__ void __launch_bounds__(256, 3)
tcn_mfma(const float* __restrict__ emb, const int* __restrict__ align_,
         const int* __restrict__ nidx, const int* __restrict__ nmask,
         const float* __restrict__ b1_0, const float* __restrict__ b2_0,
         const float* __restrict__ down_b, const float* __restrict__ b1s,
         const float* __restrict__ b2s, const short* __restrict__ Wf,
         float* __restrict__ P) {
  __shared__ char smem[41472];   // XE [81][256B] | H [81][128B] | Y [81][128B]
  __shared__ int rowid[M];
  __shared__ float mkv[G];
  char* XE = smem;
  char* Hb = smem + 20736;
  char* Yb = smem + 31104;

  const int tid = threadIdx.x;
  const int lane = tid & 63, ct = tid >> 6;
  const int blk = blockIdx.x;
  const int r = blk >> 9;
  const int blkr = blk & 511;
  const int b = blkr >> 3, chunk = blkr & 7;

  if (tid < M) {
    int g = tid / 10, t = tid - g * 10;
    int nix = (b * Rr + r) * Nn + chunk * 8 + g;
    int ent = nidx[nix];
    int msk = nmask[nix];
    int s = align_[ent * Tn + t];
    rowid[tid] = (msk != 0 && s >= 0) ? s : -1;
    if (t == 0) mkv[g] = (msk != 0) ? 1.0f : 0.0f;
  }
  if (tid >= 128 && tid < 160) *(uint64_t*)(XE + 80 * 256 + (tid - 128) * 8) = 0;
  if (tid >= 160 && tid < 176) *(uint64_t*)(Hb + 80 * 128 + (tid - 160) * 8) = 0;
  if (tid >= 176 && tid < 192) *(uint64_t*)(Yb + 80 * 128 + (tid - 176) * 8) = 0;
  __syncthreads();

  // gather: 80 rows x 128 d, f32 -> bf16, swizzled LDS write
#pragma unroll
  for (int it = 0; it < 10; ++it) {
    int idx = tid + it * 256;
    int m = idx >> 5, d4 = idx & 31;
    int row = rowid[m];
    int t = m % 10;
    s16x4 p = {0, 0, 0, 0};
    if (row >= 0) {
      const float4 v = *(const float4*)(emb + ((size_t)t * NUM_NODES + row) * 128 + d4 * 4);
      p[0] = f2bf(v.x); p[1] = f2bf(v.y); p[2] = f2bf(v.z); p[3] = f2bf(v.w);
    }
    *(s16x4*)(XE + m * 256 + ((d4 * 8) ^ ((m & 7) << 4))) = p;
  }
  __syncthreads();

  int marr[NT], tarr[NT];
#pragma unroll
  for (int tile = 0; tile < NT; ++tile) {
    marr[tile] = tile * 16 + (lane & 15);
    tarr[tile] = marr[tile] % 10;
  }

  const short* wr = Wf + r * RSTR;
  f32x4 acc[NT], acc2[NT], hreg[NT];

  // ---- level 0 ----
  conv_pass<4, 2, 0, 256>(XE, wr + OFF0, b1_0 + r * 64, 1, lane, ct, marr, tarr, acc);
#pragma unroll
  for (int tl = 0; tl < NT; ++tl)
#pragma unroll
    for (int g2 = 0; g2 < 4; ++g2) acc[tl][g2] = fmaxf(acc[tl][g2], 0.f);
  store_tiles(Yb, lane, ct, marr, acc);
  __syncthreads();
  conv_pass<2, 2, 0, 128>(Yb, wr + OFF2, b2_0 + r * 64, 1, lane, ct, marr, tarr, acc2);
  conv_pass<4, 1, 0, 256>(XE, wr + OFF1, down_b + r * 64, 0, lane, ct, marr, tarr, acc);
#pragma unroll
  for (int tl = 0; tl < NT; ++tl)
#pragma unroll
    for (int g2 = 0; g2 < 4; ++g2)
      hreg[tl][g2] = fmaxf(fmaxf(acc2[tl][g2], 0.f) + acc[tl][g2], 0.f);
  store_tiles(Hb, lane, ct, marr, hreg);
  __syncthreads();

  // ---- levels 1..7 ----
#define LEVEL(l, dd, NTAPv, TOFFv)                                                   \
  {                                                                                  \
    conv_pass<2, NTAPv, TOFFv, 128>(Hb, wr + OFFL0 + ((l - 1) * 2 + 0) * 8192,       \
                                    b1s + (r * 7 + (l - 1)) * 64, dd, lane, ct,      \
                                    marr, tarr, acc);                                \
    _Pragma("unroll") for (int tl = 0; tl < NT; ++tl)                                \
        _Pragma("unroll") for (int g2 = 0; g2 < 4; ++g2)                             \
            acc[tl][g2] = fmaxf(acc[tl][g2], 0.f);                                   \
    store_tiles(Yb, lane, ct, marr, acc);                                            \
    __syncthreads();                                                                 \
    conv_pass<2, NTAPv, TOFFv, 128>(Yb, wr + OFFL0 + ((l - 1) * 2 + 1) * 8192,       \
                                    b2s + (r * 7 + (l - 1)) * 64, dd, lane, ct,      \
                                    marr, tarr, acc);                                \
    _Pragma("unroll") for (int tl = 0; tl < NT; ++tl)                                \
        _Pragma("unroll") for (int g2 = 0; g2 < 4; ++g2)                             \
            hreg[tl][g2] = fmaxf(fmaxf(acc[tl][g2], 0.f) + hreg[tl][g2], 0.f);       \
    store_tiles(Hb, lane, ct, marr, hreg);                                           \
    __syncthreads();                                                                 \
  }
  LEVEL(1, 2, 2, 0)
  LEVEL(2, 4, 2, 0)
  LEVEL(3, 8, 2, 0)
  LEVEL(4, 16, 1, 1)
  LEVEL(5, 32, 1, 1)
  LEVEL(6, 64, 1, 1)
  LEVEL(7, 128, 1, 1)
#undef LEVEL

  // ---- epilogue: masked last-step (t==9), reduce over 8 sequences ----
  float s0 = 0, s1 = 0, s2 = 0, s3 = 0;
#pragma unroll
  for (int tl = 0; tl < NT; ++tl) {
    float mk = (tarr[tl] == 9) ? mkv[marr[tl] / 10] : 0.f;
    s0 += hreg[tl][0] * mk;
    s1 += hreg[tl][1] * mk;
    s2 += hreg[tl][2] * mk;
    s3 += hreg[tl][3] * mk;
  }
#pragma unroll
  for (int mk2 = 1; mk2 <= 8; mk2 <<= 1) {
    s0 += __shfl_xor(s0, mk2);
    s1 += __shfl_xor(s1, mk2);
    s2 += __shfl_xor(s2, mk2);
    s3 += __shfl_xor(s3, mk2);
  }
  if ((lane & 15) == 0) {
    int base = ((r * Bb + b) * 8 + chunk) * 64 + ct * 16 + (lane >> 4) * 4;
    P[base + 0] = s0;
    P[base + 1] = s1;
    P[base + 2] = s2;
    P[base + 3] = s3;
  }
}

// ---------------------------------------------------------------------------
// out[b][i] = sum_r sum_c (sum_p P[r][b][p][c]) * rel_w[r][c][i]
// ---------------------------------------------------------------------------
extern "C" __global__ void reduce_kernel(const float* __restrict__ P,
                                         const float* __restrict__ rel_w,
                                         float* __restrict__ out) {
  __shared__ float Sl[Rr * Cc];
  int b = blockIdx.x, i = threadIdx.x;
  for (int idx = i; idx < Rr * Cc; idx += 64) {
    int rr = idx >> 6, cc = idx & 63;
    float s = 0.f;
    for (int p = 0; p < 8; ++p) s += P[((rr * Bb + b) * 8 + p) * 64 + cc];
    Sl[idx] = s;
  }
  __syncthreads();
  float acc = 0.f;
  for (int r = 0; r < Rr; ++r)
#pragma unroll
    for (int cc = 0; cc < Cc; ++cc)
      acc += Sl[r * Cc + cc] * rel_w[(r * Cc + cc) * Ii + i];
  out[b * Ii + i] = acc;
}

// ---------------------------------------------------------------------------
extern "C" void kernel_launch(void* const* d_in, const int* in_sizes, int n_in,
                              void* d_out, int out_size, void* d_ws, size_t ws_size,
                              hipStream_t stream) {
  const float* emb    = (const float*)d_in[0];
  const float* w1_0   = (const float*)d_in[1];
  const float* b1_0   = (const float*)d_in[2];
  const float* w2_0   = (const float*)d_in[3];
  const float* b2_0   = (const float*)d_in[4];
  const float* down_w = (const float*)d_in[5];
  const float* down_b = (const float*)d_in[6];
  const float* w1s    = (const float*)d_in[7];
  const float* b1s    = (const float*)d_in[8];
  const float* w2s    = (const float*)d_in[9];
  const float* b2s    = (const float*)d_in[10];
  const float* rel_w  = (const float*)d_in[11];
  const int* align_   = (const int*)d_in[12];
  const int* nidx     = (const int*)d_in[13];
  const int* nmask    = (const int*)d_in[14];

  float* P  = (float*)d_ws;                       // 4*64*8*64 f32 = 512 KB
  short* Wf = (short*)((char*)d_ws + 524288);     // 589824 bf16 = 1.15 MB

  prep_kernel<<<768, 256, 0, stream>>>(w1_0, w2_0, down_w, w1s, w2s, Wf);
  tcn_mfma<<<2048, 256, 0, stream>>>(emb, align_, nidx, nmask, b1_0, b2_0, down_b,
                                     b1s, b2s, Wf, P);
  reduce_kernel<<<Bb, Cc, 0, stream>>>(P, rel_w, (float*)d_out);
}